// Round 21
// baseline (15.946 us; speedup 1.0000x reference)
//
#include <hip/hip_runtime.h>

// DLGN_VT v19 — v18 + phase-1 fully de-LDS'd (x direct from global, barrier 1 deleted):
//   512 blocks x 256 thr, 8 rows/block, launch_bounds(256,2). LDS 13.4 KB (Gs + Plds).
//   Phase 1: thread (fl=t>>3, kc=t&7) holds W1/2/3 chunks in 48 regs; x read DIRECTLY
//     from global per row (4x float4, 8-addr broadcast, L1-resident 4KB tile) — no
//     xlds, no stage, no barrier. 8 rows x 24 pk-FMA; combine k-eighths PURE VALU
//     (DPP xor1/xor2 + half-mirror); sigmoid -> Gs.
//   V loads issued after phase-1 FMA (W regs dead).
//   Phase 2: per b: g1 row via 8 uniform-broadcast ds_read_b128; g2 b32 + g3 b128;
//     64 pk-FMA i-first; p8[b] in regs.
//   Reduce: p8 -> Plds (stride 10), barrier, 8 reads + DPP + shfl xor16 -> out.
// 2 barriers total. No atomics, no memset, no global scratch.

#define BETA 30.0f

typedef float v2f __attribute__((ext_vector_type(2)));

__device__ __forceinline__ float f4c(const float4 v, int c) {
    return c == 0 ? v.x : (c == 1 ? v.y : (c == 2 ? v.z : v.w));
}

// DPP helpers: full row/bank mask, bound_ctrl=1 -> old-value-independent
__device__ __forceinline__ float qp_xor1(float a) {   // quad_perm [1,0,3,2] = 0xB1
    return __int_as_float(__builtin_amdgcn_mov_dpp(__float_as_int(a), 0xB1, 0xF, 0xF, true));
}
__device__ __forceinline__ float qp_xor2(float a) {   // quad_perm [2,3,0,1] = 0x4E
    return __int_as_float(__builtin_amdgcn_mov_dpp(__float_as_int(a), 0x4E, 0xF, 0xF, true));
}
__device__ __forceinline__ float dpp_half_mirror(float a) {   // lane i <-> 7-i within 8
    return __int_as_float(__builtin_amdgcn_mov_dpp(__float_as_int(a), 0x141, 0xF, 0xF, true));
}
__device__ __forceinline__ float dpp_row_mirror(float a) {    // lane i <-> 15-i within 16
    return __int_as_float(__builtin_amdgcn_mov_dpp(__float_as_int(a), 0x140, 0xF, 0xF, true));
}

__global__ __launch_bounds__(256, 2) void dlgn_v19_kernel(
    const float* __restrict__ x,
    const float* __restrict__ W1,
    const float* __restrict__ W2,
    const float* __restrict__ W3,
    const float* __restrict__ V,
    float* __restrict__ out)
{
    __shared__ float Gs[8][100];      //  3200 B
    __shared__ float Plds[2560];      // 10240 B: per-thread stride 10

    const int t  = threadIdx.x;
    const int b0 = blockIdx.x * 8;

    // ---- W chunks -> 48 registers (global, L2-resident) ----
    const int fl = t >> 3;   // feature-lane 0..31
    const int kc = t & 7;    // k-chunk 0..7
    float4 w1c[4], w2c[4], w3c[4];
    {
        const float4* W1r = (const float4*)(W1 + fl * 128 + kc * 16);
        const float4* W2r = (const float4*)(W2 + fl * 128 + kc * 16);
        const float4* W3r = (const float4*)(W3 + fl * 128 + kc * 16);
#pragma unroll
        for (int c = 0; c < 4; ++c) {
            w1c[c] = W1r[c]; w2c[c] = W2r[c]; w3c[c] = W3r[c];
        }
    }

    // ---- Phase 1: 8 rows x 3 matrices; x DIRECT from global (VMEM pipe, L1 tile) ----
    v2f acc2[3][8];
#pragma unroll
    for (int m = 0; m < 3; ++m)
#pragma unroll
        for (int r = 0; r < 8; ++r) acc2[m][r] = (v2f){0.f, 0.f};

#pragma unroll
    for (int r = 0; r < 8; ++r) {
        const float4* xr = (const float4*)(x + (size_t)(b0 + r) * 128 + kc * 16);
        float4 xc[4];
#pragma unroll
        for (int c = 0; c < 4; ++c) xc[c] = xr[c];
#pragma unroll
        for (int c = 0; c < 4; ++c) {
            const v2f xlo = (v2f){xc[c].x, xc[c].y};
            const v2f xhi = (v2f){xc[c].z, xc[c].w};
            acc2[0][r] = __builtin_elementwise_fma((v2f){w1c[c].x, w1c[c].y}, xlo, acc2[0][r]);
            acc2[0][r] = __builtin_elementwise_fma((v2f){w1c[c].z, w1c[c].w}, xhi, acc2[0][r]);
            acc2[1][r] = __builtin_elementwise_fma((v2f){w2c[c].x, w2c[c].y}, xlo, acc2[1][r]);
            acc2[1][r] = __builtin_elementwise_fma((v2f){w2c[c].z, w2c[c].w}, xhi, acc2[1][r]);
            acc2[2][r] = __builtin_elementwise_fma((v2f){w3c[c].x, w3c[c].y}, xlo, acc2[2][r]);
            acc2[2][r] = __builtin_elementwise_fma((v2f){w3c[c].z, w3c[c].w}, xhi, acc2[2][r]);
        }
    }

    // ---- Issue V loads now (W regs dead); complete under combine + barrier ----
    const float4* V4 = (const float4*)V;   // f4 idx = i*256 + t
    float4 v[32];
#pragma unroll
    for (int i = 0; i < 32; ++i) v[i] = V4[i * 256 + t];

    // ---- Combine k-eighths: PURE VALU (DPP xor1, xor2, half-mirror); sigmoid -> Gs ----
#pragma unroll
    for (int m = 0; m < 3; ++m) {
        float sel = 0.f;
#pragma unroll
        for (int r = 0; r < 8; ++r) {
            float a = acc2[m][r].x + acc2[m][r].y;
            a += qp_xor1(a);
            a += qp_xor2(a);          // each quad holds its quad-sum
            a += dpp_half_mirror(a);  // + opposite quad -> full 8-sum
            if (kc == r) sel = a;     // static select chain
        }
        Gs[kc][32 * m + fl] = 1.0f / (1.0f + __expf(-BETA * sel));
    }
    __syncthreads();

    // ---- Phase 2: thread = (j = t>>3, c2 = t&7); g1 via LDS broadcast into VGPRs ----
    const int j  = t >> 3;   // [0,32)
    const int c2 = t & 7;    // [0,8)

    float p8[8];
#pragma unroll
    for (int b = 0; b < 8; ++b) {
        const float4* Gr = (const float4*)&Gs[b][0];
        float4 g1r[8];
#pragma unroll
        for (int c = 0; c < 8; ++c) g1r[c] = Gr[c];    // uniform broadcast, conflict-free
        const float  g2s = Gs[b][32 + j];
        const float4 g3r = *(const float4*)&Gs[b][64 + c2 * 4];

        v2f u2a = (v2f){0.f, 0.f};   // {x,y} accumulator
        v2f u2b = (v2f){0.f, 0.f};   // {z,w} accumulator
#pragma unroll
        for (int i = 0; i < 32; ++i) {
            const float g1i = f4c(g1r[i >> 2], i & 3);   // static reg pick
            const v2f g1v = (v2f){g1i, g1i};
            u2a = __builtin_elementwise_fma(g1v, (v2f){v[i].x, v[i].y}, u2a);
            u2b = __builtin_elementwise_fma(g1v, (v2f){v[i].z, v[i].w}, u2b);
        }
        float s = u2a.x * g3r.x;
        s = fmaf(u2a.y, g3r.y, s);
        s = fmaf(u2b.x, g3r.z, s);
        s = fmaf(u2b.y, g3r.w, s);
        p8[b] = s * g2s;
    }

    // ---- Deferred reduction: 2 packed b128 writes, barrier, DPP-heavy final pass ----
    *(float4*)&Plds[t * 10]     = make_float4(p8[0], p8[1], p8[2], p8[3]);
    *(float4*)&Plds[t * 10 + 4] = make_float4(p8[4], p8[5], p8[6], p8[7]);
    __syncthreads();

    {
        const int fb2 = t >> 5;   // b index 0..7
        const int pt  = t & 31;   // partial index
        float s = 0.f;
#pragma unroll
        for (int s8 = 0; s8 < 8; ++s8)
            s += Plds[(pt + s8 * 32) * 10 + fb2];
        s += qp_xor1(s);
        s += qp_xor2(s);
        s += dpp_half_mirror(s);   // 8-sum
        s += dpp_row_mirror(s);    // 16-sum
        s += __shfl_xor(s, 16);    // 32-sum (crosses DPP row boundary)
        if (pt == 0) out[b0 + fb2] = s;
    }
}

extern "C" void kernel_launch(void* const* d_in, const int* in_sizes, int n_in,
                              void* d_out, int out_size, void* d_ws, size_t ws_size,
                              hipStream_t stream) {
    const float* x  = (const float*)d_in[0];
    const float* W1 = (const float*)d_in[1];
    const float* W2 = (const float*)d_in[2];
    const float* W3 = (const float*)d_in[3];
    const float* V  = (const float*)d_in[4];
    float* out = (float*)d_out;

    dlgn_v19_kernel<<<dim3(512), dim3(256), 0, stream>>>(x, W1, W2, W3, V, out);
}

// Round 22
// 12.738 us; speedup vs baseline: 1.2519x; 1.2519x over previous
//
#include <hip/hip_runtime.h>

// DLGN_VT v20 — v18 base + phase-2 i-split (vbuf[16] x2) + launch_bounds(256,3):
//   Drops VGPR peak ~200 -> ~140 so 3 blocks/CU co-reside (3 waves/SIMD, +50%
//   latency hiding) at IDENTICAL instruction count. v18 structure otherwise:
//   512 blocks x 256 thr, 8 rows/block; x kc-skewed in LDS; W in 48 regs;
//   8 rows x 24 pk-FMA; pure-DPP combine; sigmoid -> Gs.
//   Phase 2: i-half 0: load vbuf[16] (issued before combine), per b: 4 uniform
//   ds_read_b128 (g1 low) + 32 pk-FMA into ua/ub[b]; i-half 1: reload vbuf, g1 high;
//   finalize p8[b] = dot(u,g3)*g2. Reduce via Plds + DPP.
// No atomics, no memset, no global scratch.

#define BETA 30.0f

typedef float v2f __attribute__((ext_vector_type(2)));

__device__ __forceinline__ float f4c(const float4 v, int c) {
    return c == 0 ? v.x : (c == 1 ? v.y : (c == 2 ? v.z : v.w));
}

// DPP helpers: full row/bank mask, bound_ctrl=1 -> old-value-independent
__device__ __forceinline__ float qp_xor1(float a) {   // quad_perm [1,0,3,2] = 0xB1
    return __int_as_float(__builtin_amdgcn_mov_dpp(__float_as_int(a), 0xB1, 0xF, 0xF, true));
}
__device__ __forceinline__ float qp_xor2(float a) {   // quad_perm [2,3,0,1] = 0x4E
    return __int_as_float(__builtin_amdgcn_mov_dpp(__float_as_int(a), 0x4E, 0xF, 0xF, true));
}
__device__ __forceinline__ float dpp_half_mirror(float a) {   // lane i <-> 7-i within 8
    return __int_as_float(__builtin_amdgcn_mov_dpp(__float_as_int(a), 0x141, 0xF, 0xF, true));
}
__device__ __forceinline__ float dpp_row_mirror(float a) {    // lane i <-> 15-i within 16
    return __int_as_float(__builtin_amdgcn_mov_dpp(__float_as_int(a), 0x140, 0xF, 0xF, true));
}

__global__ __launch_bounds__(256, 3) void dlgn_v20_kernel(
    const float* __restrict__ x,
    const float* __restrict__ W1,
    const float* __restrict__ W2,
    const float* __restrict__ W3,
    const float* __restrict__ V,
    float* __restrict__ out)
{
    __shared__ float xlds[8 * 160];   //  5120 B: kc-chunk stride 20
    __shared__ float Gs[8][100];      //  3200 B
    __shared__ float Plds[2560];      // 10240 B: per-thread stride 10

    const int t  = threadIdx.x;
    const int b0 = blockIdx.x * 8;

    // ---- Stage x tile: 1 float4/thread, coalesced; kc-skewed layout ----
    {
        const int r    = t >> 5;
        const int col4 = t & 31;
        const float4 xv = ((const float4*)(x + (size_t)(b0 + r) * 128))[col4];
        const int skc = col4 >> 2, sc = col4 & 3;
        *(float4*)&xlds[r * 160 + skc * 20 + sc * 4] = xv;
    }

    // ---- W chunks -> 48 registers (global, L2-resident) ----
    const int fl = t >> 3;   // feature-lane 0..31
    const int kc = t & 7;    // k-chunk 0..7
    float4 w1c[4], w2c[4], w3c[4];
    {
        const float4* W1r = (const float4*)(W1 + fl * 128 + kc * 16);
        const float4* W2r = (const float4*)(W2 + fl * 128 + kc * 16);
        const float4* W3r = (const float4*)(W3 + fl * 128 + kc * 16);
#pragma unroll
        for (int c = 0; c < 4; ++c) {
            w1c[c] = W1r[c]; w2c[c] = W2r[c]; w3c[c] = W3r[c];
        }
    }
    __syncthreads();   // xlds ready

    // ---- Phase 1: 8 rows x 3 matrices, packed k-eighth partial dots ----
    v2f acc2[3][8];
#pragma unroll
    for (int m = 0; m < 3; ++m)
#pragma unroll
        for (int r = 0; r < 8; ++r) acc2[m][r] = (v2f){0.f, 0.f};

#pragma unroll
    for (int r = 0; r < 8; ++r) {
        float4 xc[4];
#pragma unroll
        for (int c = 0; c < 4; ++c)
            xc[c] = *(const float4*)&xlds[r * 160 + kc * 20 + c * 4];
#pragma unroll
        for (int c = 0; c < 4; ++c) {
            const v2f xlo = (v2f){xc[c].x, xc[c].y};
            const v2f xhi = (v2f){xc[c].z, xc[c].w};
            acc2[0][r] = __builtin_elementwise_fma((v2f){w1c[c].x, w1c[c].y}, xlo, acc2[0][r]);
            acc2[0][r] = __builtin_elementwise_fma((v2f){w1c[c].z, w1c[c].w}, xhi, acc2[0][r]);
            acc2[1][r] = __builtin_elementwise_fma((v2f){w2c[c].x, w2c[c].y}, xlo, acc2[1][r]);
            acc2[1][r] = __builtin_elementwise_fma((v2f){w2c[c].z, w2c[c].w}, xhi, acc2[1][r]);
            acc2[2][r] = __builtin_elementwise_fma((v2f){w3c[c].x, w3c[c].y}, xlo, acc2[2][r]);
            acc2[2][r] = __builtin_elementwise_fma((v2f){w3c[c].z, w3c[c].w}, xhi, acc2[2][r]);
        }
    }

    // ---- Issue first V half now (W regs dead); completes under combine + barrier ----
    const float4* V4 = (const float4*)V;   // f4 idx = i*256 + t
    float4 vbuf[16];
#pragma unroll
    for (int i = 0; i < 16; ++i) vbuf[i] = V4[i * 256 + t];

    // ---- Combine k-eighths: PURE VALU (DPP xor1, xor2, half-mirror); sigmoid -> Gs ----
#pragma unroll
    for (int m = 0; m < 3; ++m) {
        float sel = 0.f;
#pragma unroll
        for (int r = 0; r < 8; ++r) {
            float a = acc2[m][r].x + acc2[m][r].y;
            a += qp_xor1(a);
            a += qp_xor2(a);          // each quad holds its quad-sum
            a += dpp_half_mirror(a);  // + opposite quad -> full 8-sum
            if (kc == r) sel = a;     // static select chain
        }
        Gs[kc][32 * m + fl] = 1.0f / (1.0f + __expf(-BETA * sel));
    }
    __syncthreads();

    // ---- Phase 2: i-split into two halves; u-accumulators live across halves ----
    const int j  = t >> 3;   // [0,32)
    const int c2 = t & 7;    // [0,8)

    v2f ua[8], ub[8];
#pragma unroll
    for (int b = 0; b < 8; ++b) { ua[b] = (v2f){0.f, 0.f}; ub[b] = (v2f){0.f, 0.f}; }

    // -- half 0: i = 0..15 (g1 regs Gr[0..3]) --
#pragma unroll
    for (int b = 0; b < 8; ++b) {
        const float4* Gr = (const float4*)&Gs[b][0];
        float4 g1r[4];
#pragma unroll
        for (int c = 0; c < 4; ++c) g1r[c] = Gr[c];    // uniform broadcast
#pragma unroll
        for (int i = 0; i < 16; ++i) {
            const float g1i = f4c(g1r[i >> 2], i & 3);
            const v2f g1v = (v2f){g1i, g1i};
            ua[b] = __builtin_elementwise_fma(g1v, (v2f){vbuf[i].x, vbuf[i].y}, ua[b]);
            ub[b] = __builtin_elementwise_fma(g1v, (v2f){vbuf[i].z, vbuf[i].w}, ub[b]);
        }
    }

    // -- reload vbuf with second V half: i = 16..31 --
#pragma unroll
    for (int i = 0; i < 16; ++i) vbuf[i] = V4[(16 + i) * 256 + t];

#pragma unroll
    for (int b = 0; b < 8; ++b) {
        const float4* Gr = (const float4*)&Gs[b][0];
        float4 g1r[4];
#pragma unroll
        for (int c = 0; c < 4; ++c) g1r[c] = Gr[4 + c];   // g1 high half
#pragma unroll
        for (int i = 0; i < 16; ++i) {
            const float g1i = f4c(g1r[i >> 2], i & 3);
            const v2f g1v = (v2f){g1i, g1i};
            ua[b] = __builtin_elementwise_fma(g1v, (v2f){vbuf[i].x, vbuf[i].y}, ua[b]);
            ub[b] = __builtin_elementwise_fma(g1v, (v2f){vbuf[i].z, vbuf[i].w}, ub[b]);
        }
    }

    // -- finalize: p8[b] = dot(u, g3) * g2 --
    float p8[8];
#pragma unroll
    for (int b = 0; b < 8; ++b) {
        const float  g2s = Gs[b][32 + j];
        const float4 g3r = *(const float4*)&Gs[b][64 + c2 * 4];
        float s = ua[b].x * g3r.x;
        s = fmaf(ua[b].y, g3r.y, s);
        s = fmaf(ub[b].x, g3r.z, s);
        s = fmaf(ub[b].y, g3r.w, s);
        p8[b] = s * g2s;
    }

    // ---- Deferred reduction: 2 packed b128 writes, barrier, DPP-heavy final pass ----
    *(float4*)&Plds[t * 10]     = make_float4(p8[0], p8[1], p8[2], p8[3]);
    *(float4*)&Plds[t * 10 + 4] = make_float4(p8[4], p8[5], p8[6], p8[7]);
    __syncthreads();

    {
        const int fb2 = t >> 5;   // b index 0..7
        const int pt  = t & 31;   // partial index
        float s = 0.f;
#pragma unroll
        for (int s8 = 0; s8 < 8; ++s8)
            s += Plds[(pt + s8 * 32) * 10 + fb2];
        s += qp_xor1(s);
        s += qp_xor2(s);
        s += dpp_half_mirror(s);   // 8-sum
        s += dpp_row_mirror(s);    // 16-sum
        s += __shfl_xor(s, 16);    // 32-sum (crosses DPP row boundary)
        if (pt == 0) out[b0 + fb2] = s;
    }
}

extern "C" void kernel_launch(void* const* d_in, const int* in_sizes, int n_in,
                              void* d_out, int out_size, void* d_ws, size_t ws_size,
                              hipStream_t stream) {
    const float* x  = (const float*)d_in[0];
    const float* W1 = (const float*)d_in[1];
    const float* W2 = (const float*)d_in[2];
    const float* W3 = (const float*)d_in[3];
    const float* V  = (const float*)d_in[4];
    float* out = (float*)d_out;

    dlgn_v20_kernel<<<dim3(512), dim3(256), 0, stream>>>(x, W1, W2, W3, V, out);
}

// Round 23
// 12.692 us; speedup vs baseline: 1.2563x; 1.0036x over previous
//
#include <hip/hip_runtime.h>

// DLGN_VT v21 — v18 base + wave-private x staging (deletes barrier 1) + setprio(phase-2)
//   + g2/g3 hoist:
//   512 blocks x 256 thr, 8 rows/block, launch_bounds(256,2). LDS 34.4 KB -> 2 blocks/CU.
//   Stage: each WAVE stages all 8 x rows into its OWN xlds copy (4 f4/lane, contiguous
//     4KB read; row stride 164 keeps writes <=2-way, reads 8-addr conflict-free).
//     ds_write -> ds_read is wave-local: lgkmcnt only, NO s_barrier -> waves desync.
//   Phase 1 (= v18): W1/2/3 chunks in 48 regs; 8 rows x 24 pk-FMA; pure-DPP combine
//     (xor1/xor2/half-mirror); sigmoid -> Gs[8][100].  V loads issued after FMA.
//   Phase 2 (= v18 + hoisted g2/g3, setprio(1) around the FMA cluster): per b,
//     g1 via 8 uniform ds_read_b128; 64 pk-FMA i-first; p8[b] in regs.
//   Reduce: p8 -> Plds (stride 10), barrier, 8 reads + DPP + shfl xor16 -> out.
// 2 barriers total. No atomics, no memset, no global scratch.

#define BETA 30.0f

typedef float v2f __attribute__((ext_vector_type(2)));

__device__ __forceinline__ float f4c(const float4 v, int c) {
    return c == 0 ? v.x : (c == 1 ? v.y : (c == 2 ? v.z : v.w));
}

// DPP helpers: full row/bank mask, bound_ctrl=1 -> old-value-independent
__device__ __forceinline__ float qp_xor1(float a) {   // quad_perm [1,0,3,2] = 0xB1
    return __int_as_float(__builtin_amdgcn_mov_dpp(__float_as_int(a), 0xB1, 0xF, 0xF, true));
}
__device__ __forceinline__ float qp_xor2(float a) {   // quad_perm [2,3,0,1] = 0x4E
    return __int_as_float(__builtin_amdgcn_mov_dpp(__float_as_int(a), 0x4E, 0xF, 0xF, true));
}
__device__ __forceinline__ float dpp_half_mirror(float a) {   // lane i <-> 7-i within 8
    return __int_as_float(__builtin_amdgcn_mov_dpp(__float_as_int(a), 0x141, 0xF, 0xF, true));
}
__device__ __forceinline__ float dpp_row_mirror(float a) {    // lane i <-> 15-i within 16
    return __int_as_float(__builtin_amdgcn_mov_dpp(__float_as_int(a), 0x140, 0xF, 0xF, true));
}

__global__ __launch_bounds__(256, 2) void dlgn_v21_kernel(
    const float* __restrict__ x,
    const float* __restrict__ W1,
    const float* __restrict__ W2,
    const float* __restrict__ W3,
    const float* __restrict__ V,
    float* __restrict__ out)
{
    __shared__ float xlds[4 * 1312];  // 20992 B: per-wave copy, row stride 164
    __shared__ float Gs[8][100];      //  3200 B
    __shared__ float Plds[2560];      // 10240 B: per-thread stride 10

    const int t  = threadIdx.x;
    const int b0 = blockIdx.x * 8;
    const int wv = t >> 6;
    const int l  = t & 63;

    // ---- Wave-private x stage: 4 f4/lane, contiguous 4KB per wave; NO barrier ----
    {
        float* xw = &xlds[wv * 1312];
        const float4* xg = (const float4*)(x + (size_t)b0 * 128);
#pragma unroll
        for (int q = 0; q < 4; ++q) {
            const int idx  = l * 4 + q;        // [0,256) = r*32 + col4
            const int r    = idx >> 5;
            const int col4 = idx & 31;
            const float4 xv = xg[idx];
            *(float4*)&xw[r * 164 + (col4 >> 2) * 20 + (col4 & 3) * 4] = xv;
        }
    }

    // ---- W chunks -> 48 registers (global, L2-resident) ----
    const int fl = t >> 3;   // feature-lane 0..31 (within wave: 8 values)
    const int kc = t & 7;    // k-chunk 0..7
    float4 w1c[4], w2c[4], w3c[4];
    {
        const float4* W1r = (const float4*)(W1 + fl * 128 + kc * 16);
        const float4* W2r = (const float4*)(W2 + fl * 128 + kc * 16);
        const float4* W3r = (const float4*)(W3 + fl * 128 + kc * 16);
#pragma unroll
        for (int c = 0; c < 4; ++c) {
            w1c[c] = W1r[c]; w2c[c] = W2r[c]; w3c[c] = W3r[c];
        }
    }
    // (compiler inserts vmcnt before ds_write, lgkmcnt before first xlds read)

    // ---- Phase 1: 8 rows x 3 matrices, packed k-eighth partial dots ----
    v2f acc2[3][8];
#pragma unroll
    for (int m = 0; m < 3; ++m)
#pragma unroll
        for (int r = 0; r < 8; ++r) acc2[m][r] = (v2f){0.f, 0.f};

    {
        const float* xw = &xlds[wv * 1312];
#pragma unroll
        for (int r = 0; r < 8; ++r) {
            float4 xc[4];
#pragma unroll
            for (int c = 0; c < 4; ++c)
                xc[c] = *(const float4*)&xw[r * 164 + kc * 20 + c * 4];
#pragma unroll
            for (int c = 0; c < 4; ++c) {
                const v2f xlo = (v2f){xc[c].x, xc[c].y};
                const v2f xhi = (v2f){xc[c].z, xc[c].w};
                acc2[0][r] = __builtin_elementwise_fma((v2f){w1c[c].x, w1c[c].y}, xlo, acc2[0][r]);
                acc2[0][r] = __builtin_elementwise_fma((v2f){w1c[c].z, w1c[c].w}, xhi, acc2[0][r]);
                acc2[1][r] = __builtin_elementwise_fma((v2f){w2c[c].x, w2c[c].y}, xlo, acc2[1][r]);
                acc2[1][r] = __builtin_elementwise_fma((v2f){w2c[c].z, w2c[c].w}, xhi, acc2[1][r]);
                acc2[2][r] = __builtin_elementwise_fma((v2f){w3c[c].x, w3c[c].y}, xlo, acc2[2][r]);
                acc2[2][r] = __builtin_elementwise_fma((v2f){w3c[c].z, w3c[c].w}, xhi, acc2[2][r]);
            }
        }
    }

    // ---- Issue V loads now (W regs dead); complete under combine + barrier ----
    const float4* V4 = (const float4*)V;   // f4 idx = i*256 + t
    float4 v[32];
#pragma unroll
    for (int i = 0; i < 32; ++i) v[i] = V4[i * 256 + t];

    // ---- Combine k-eighths: PURE VALU (DPP xor1, xor2, half-mirror); sigmoid -> Gs ----
#pragma unroll
    for (int m = 0; m < 3; ++m) {
        float sel = 0.f;
#pragma unroll
        for (int r = 0; r < 8; ++r) {
            float a = acc2[m][r].x + acc2[m][r].y;
            a += qp_xor1(a);
            a += qp_xor2(a);          // each quad holds its quad-sum
            a += dpp_half_mirror(a);  // + opposite quad -> full 8-sum
            if (kc == r) sel = a;     // static select chain
        }
        Gs[kc][32 * m + fl] = 1.0f / (1.0f + __expf(-BETA * sel));
    }
    __syncthreads();

    // ---- Phase 2: hoist g2/g3; setprio(1) around the FMA cluster ----
    const int j  = t >> 3;   // [0,32)
    const int c2 = t & 7;    // [0,8)

    float  g2v[8];
    float4 g3v[8];
#pragma unroll
    for (int b = 0; b < 8; ++b) {
        g2v[b] = Gs[b][32 + j];
        g3v[b] = *(const float4*)&Gs[b][64 + c2 * 4];
    }

    __builtin_amdgcn_s_setprio(1);
    float p8[8];
#pragma unroll
    for (int b = 0; b < 8; ++b) {
        const float4* Gr = (const float4*)&Gs[b][0];
        float4 g1r[8];
#pragma unroll
        for (int c = 0; c < 8; ++c) g1r[c] = Gr[c];    // uniform broadcast, conflict-free

        v2f u2a = (v2f){0.f, 0.f};   // {x,y} accumulator
        v2f u2b = (v2f){0.f, 0.f};   // {z,w} accumulator
#pragma unroll
        for (int i = 0; i < 32; ++i) {
            const float g1i = f4c(g1r[i >> 2], i & 3);   // static reg pick
            const v2f g1v = (v2f){g1i, g1i};
            u2a = __builtin_elementwise_fma(g1v, (v2f){v[i].x, v[i].y}, u2a);
            u2b = __builtin_elementwise_fma(g1v, (v2f){v[i].z, v[i].w}, u2b);
        }
        float s = u2a.x * g3v[b].x;
        s = fmaf(u2a.y, g3v[b].y, s);
        s = fmaf(u2b.x, g3v[b].z, s);
        s = fmaf(u2b.y, g3v[b].w, s);
        p8[b] = s * g2v[b];
    }
    __builtin_amdgcn_s_setprio(0);

    // ---- Deferred reduction: 2 packed b128 writes, barrier, DPP-heavy final pass ----
    *(float4*)&Plds[t * 10]     = make_float4(p8[0], p8[1], p8[2], p8[3]);
    *(float4*)&Plds[t * 10 + 4] = make_float4(p8[4], p8[5], p8[6], p8[7]);
    __syncthreads();

    {
        const int fb2 = t >> 5;   // b index 0..7
        const int pt  = t & 31;   // partial index
        float s = 0.f;
#pragma unroll
        for (int s8 = 0; s8 < 8; ++s8)
            s += Plds[(pt + s8 * 32) * 10 + fb2];
        s += qp_xor1(s);
        s += qp_xor2(s);
        s += dpp_half_mirror(s);   // 8-sum
        s += dpp_row_mirror(s);    // 16-sum
        s += __shfl_xor(s, 16);    // 32-sum (crosses DPP row boundary)
        if (pt == 0) out[b0 + fb2] = s;
    }
}

extern "C" void kernel_launch(void* const* d_in, const int* in_sizes, int n_in,
                              void* d_out, int out_size, void* d_ws, size_t ws_size,
                              hipStream_t stream) {
    const float* x  = (const float*)d_in[0];
    const float* W1 = (const float*)d_in[1];
    const float* W2 = (const float*)d_in[2];
    const float* W3 = (const float*)d_in[3];
    const float* V  = (const float*)d_in[4];
    float* out = (float*)d_out;

    dlgn_v21_kernel<<<dim3(512), dim3(256), 0, stream>>>(x, W1, W2, W3, V, out);
}